// Round 33
// baseline (132.061 us; speedup 1.0000x reference)
//
#include <hip/hip_runtime.h>

// TransformerConvolution (graph attention with per-edge keys), MI355X gfx950.
// Rewrite: q_j . (edge_ij @ We_k) == edge_ij . (We_k^T q_j) = edge . qe_j
//
// R33: latency chain = per-h qe load -> FMA -> butterfly, repeated per
// 4-row block. Amortize over 8 i-rows/block: halves qe/k/adj traffic,
// doubles FMA per exposed qe-load latency (80:4 vs 40:4).

__device__ inline float guard_relu(float x) {
    if (x != x) return 0.0f;
    return fmaxf(x, 0.0f);
}

// ---------- Kernel 1: z@{Wq,Wk,Wv}, qe = We_k^T q  (256 blocks x 256) ------
__global__ void tc29_prep(
    const float* node, const float* hidden,
    const float* Wq, const float* Wk, const float* Wv, const float* Wek,
    float* qbuf, float* kbuf, float* vbuf, float* qebuf)
{
    __shared__ float z[4][128];
    __shared__ float qs[4][128];
    const int t = threadIdx.x;
    const int r0 = blockIdx.x * 4;            // global row = b*512 + n

    for (int kk = 0; kk < 2; ++kk) {
        int idx = t + kk * 256;               // 0..511
        int r = idx >> 7, c = idx & 127;
        int row = r0 + r;
        z[r][c] = (c < 64) ? node[row * 64 + c] : hidden[row * 64 + (c - 64)];
    }
    __syncthreads();

    const int o  = t & 127;
    const int rh = t >> 7;                    // rows rh and rh+2
    float aq0 = 0.f, aq1 = 0.f, ak0 = 0.f, ak1 = 0.f, av0 = 0.f, av1 = 0.f;
    for (int c = 0; c < 128; ++c) {
        float wq = Wq[c * 128 + o], wk = Wk[c * 128 + o], wv = Wv[c * 128 + o];
        float z0 = z[rh][c], z1 = z[rh + 2][c];
        aq0 = fmaf(z0, wq, aq0); aq1 = fmaf(z1, wq, aq1);
        ak0 = fmaf(z0, wk, ak0); ak1 = fmaf(z1, wk, ak1);
        av0 = fmaf(z0, wv, av0); av1 = fmaf(z1, wv, av1);
    }
    {
        int row0 = r0 + rh, row1 = r0 + rh + 2;
        qbuf[row0 * 128 + o] = aq0; qbuf[row1 * 128 + o] = aq1;
        kbuf[row0 * 128 + o] = ak0; kbuf[row1 * 128 + o] = ak1;
        vbuf[row0 * 128 + o] = av0; vbuf[row1 * 128 + o] = av1;
        qs[rh][o] = aq0; qs[rh + 2][o] = aq1;
    }
    __syncthreads();

    // qe[row][h][c] = sum_d q[row][h*16+d] * Wek[c*128 + h*16 + d]
    for (int kk = 0; kk < 2; ++kk) {
        int hc = t + kk * 256;                // 0..511
        int h = hc >> 6, c = hc & 63;
        for (int r = 0; r < 4; ++r) {
            float s = 0.f;
            for (int d = 0; d < 16; ++d)
                s = fmaf(qs[r][h * 16 + d], Wek[c * 128 + h * 16 + d], s);
            qebuf[((r0 + r) * 8 + h) * 64 + c] = s;
        }
    }
}

// ---------- Kernel 2: 8-row group-score attention (1024 blocks x 256) ------
// block = (b, i-octet(8 rows), j-chunk of 64). 32 groups x 8 lanes own the
// c-axis (coalesced); qe/k loads amortized over 8 rows; shfl butterfly.
__global__ void tc29_attn(
    const float* edge, const float* adj,
    const float* qbuf, const float* kbuf, const float* vbuf,
    const float* qebuf, float* pacc, float* pden)
{
    __shared__ float qls[8][132];
    __shared__ float els[8][8][66];
    const int t   = threadIdx.x;
    const int bid = blockIdx.x;
    const int jq  = bid & 7;                  // 8 chunks of 64 j
    const int it  = (bid >> 3) & 63;          // i-octet
    const int b   = bid >> 9;
    const int i0  = it * 8;

    for (int kk = 0; kk < 4; ++kk) {
        int idx = t + kk * 256;               // 0..1023
        int r = idx >> 7, c = idx & 127;
        qls[r][c] = qbuf[(size_t)(b * 512 + i0 + r) * 128 + c];
    }
    __syncthreads();

    const int g = t >> 3;                     // group 0..31
    const int l = t & 7;                      // lane in group

    for (int u = 0; u < 2; ++u) {
        const int jl = g + u * 32;
        const int j  = jq * 64 + jl;
        const float* er0 = edge + ((size_t)(b * 512 + i0) * 512 + j) * 64 + l * 8;
        float4 ea[8], eb[8];
        #pragma unroll
        for (int r = 0; r < 8; ++r) {
            const float* er = er0 + (size_t)r * 512 * 64;
            ea[r] = *(const float4*)(er);
            eb[r] = *(const float4*)(er + 4);
        }
        float am[8];
        #pragma unroll
        for (int r = 0; r < 8; ++r)
            am[r] = adj[(size_t)(b * 512 + i0 + r) * 512 + j];
        const float* qerow = qebuf + (size_t)(b * 512 + j) * 512 + l * 8;
        const float* krow  = kbuf  + (size_t)(b * 512 + j) * 128;

        #pragma unroll
        for (int h = 0; h < 8; ++h) {
            float4 qa = *(const float4*)(qerow + h * 64);
            float4 qb = *(const float4*)(qerow + h * 64 + 4);
            float k0 = krow[h * 16 + l];
            float k1 = krow[h * 16 + 8 + l];
            float p[8];
            #pragma unroll
            for (int r = 0; r < 8; ++r) {
                float qv  = qls[r][h * 16 + l];
                float qvb = qls[r][h * 16 + 8 + l];
                p[r] = ea[r].x*qa.x + ea[r].y*qa.y + ea[r].z*qa.z + ea[r].w*qa.w
                     + eb[r].x*qb.x + eb[r].y*qb.y + eb[r].z*qb.z + eb[r].w*qb.w
                     + k0 * qv + k1 * qvb;
            }
            #pragma unroll
            for (int m = 4; m >= 1; m >>= 1) {
                #pragma unroll
                for (int r = 0; r < 8; ++r)
                    p[r] += __shfl_xor(p[r], m, 64);   // within 8-lane group
            }
            if (l == h) {
                #pragma unroll
                for (int r = 0; r < 8; ++r)
                    els[r][h][jl] = am[r] * __expf(p[r] * 0.25f);
            }
        }
    }
    __syncthreads();

    // ---- PV partials over this 64-j chunk; each thread does 4 rows ----
    const int o  = t & 127;                   // outdim (h*16+d)
    const int ip = (t >> 7) * 4;              // rows ip..ip+3
    const int hB = o >> 4;
    const float* vbase = vbuf + ((size_t)(b * 512) + jq * 64) * 128 + o;
    float acc[4] = {0.f, 0.f, 0.f, 0.f};
    float den[4] = {0.f, 0.f, 0.f, 0.f};
    for (int jl = 0; jl < 64; ++jl) {
        float v = vbase[(size_t)jl * 128];
        #pragma unroll
        for (int rr = 0; rr < 4; ++rr) {
            float e = els[ip + rr][hB][jl];
            acc[rr] = fmaf(e, v, acc[rr]);
            den[rr] += e;
        }
    }
    #pragma unroll
    for (int rr = 0; rr < 4; ++rr) {
        size_t ix = ((size_t)(b * 512 + i0 + ip + rr) * 8 + jq) * 128 + o;
        pacc[ix] = acc[rr];
        pden[ix] = den[rr];
    }
}

// ---------- Kernel 3: merge 8 chunks + Wo + FFN, f32 store -----------------
__global__ void tc29_post(
    const float* pacc, const float* pden,
    const float* Wo, const float* W1,
    const float* b1f, const float* W2, const float* b2f,
    float* __restrict__ out)
{
    __shared__ float a[4][128];
    __shared__ float y[4][128];
    const int t = threadIdx.x;
    const int o = t & 127, rh = t >> 7;
    const int r0 = blockIdx.x * 4;

    for (int m = 0; m < 2; ++m) {
        int r = rh + 2 * m;
        int row = r0 + r;
        float s = 0.f, d = 0.f;
        #pragma unroll
        for (int q = 0; q < 8; ++q) {
            size_t idx = ((size_t)row * 8 + q) * 128 + o;
            s += pacc[idx];
            d += pden[idx];
        }
        a[r][o] = s / d;                       // adj self-loops -> d > 0
    }
    __syncthreads();

    float acc0 = 0.f, acc1 = 0.f;
    for (int c = 0; c < 128; ++c) {
        float w = Wo[c * 128 + o];
        acc0 = fmaf(a[rh][c], w, acc0);
        acc1 = fmaf(a[rh + 2][c], w, acc1);
    }
    y[rh][o] = acc0; y[rh + 2][o] = acc1;
    __syncthreads();

    acc0 = 0.f; acc1 = 0.f;
    for (int c = 0; c < 128; ++c) {
        float w = W1[c * 128 + o];
        acc0 = fmaf(y[rh][c], w, acc0);
        acc1 = fmaf(y[rh + 2][c], w, acc1);
    }
    float bb = b1f[o];
    __syncthreads();
    a[rh][o]     = guard_relu(acc0 + bb);
    a[rh + 2][o] = guard_relu(acc1 + bb);
    __syncthreads();

    acc0 = 0.f; acc1 = 0.f;
    for (int c = 0; c < 128; ++c) {
        float w = W2[c * 128 + o];
        acc0 = fmaf(a[rh][c], w, acc0);
        acc1 = fmaf(a[rh + 2][c], w, acc1);
    }
    float bb2 = b2f[o];
    int row0 = r0 + rh, row1 = r0 + rh + 2;
    out[row0 * 128 + o] = guard_relu(acc0 + bb2);   // FLOAT32 store
    out[row1 * 128 + o] = guard_relu(acc1 + bb2);
}

extern "C" void kernel_launch(void* const* d_in, const int* in_sizes, int n_in,
                              void* d_out, int out_size, void* d_ws, size_t ws_size,
                              hipStream_t stream) {
    (void)in_sizes; (void)n_in; (void)out_size; (void)ws_size;

    const float* node   = (const float*)d_in[0];
    const float* edge   = (const float*)d_in[1];
    const float* hidden = (const float*)d_in[3];   // d_in[2] = graph_fts, unused
    const float* adj    = (const float*)d_in[4];
    const float* Wq     = (const float*)d_in[5];
    const float* Wk     = (const float*)d_in[6];
    const float* Wv     = (const float*)d_in[7];
    const float* Wo     = (const float*)d_in[8];
    const float* Wek    = (const float*)d_in[9];
    const float* W1     = (const float*)d_in[10];
    const float* b1f    = (const float*)d_in[11];
    const float* W2     = (const float*)d_in[12];
    const float* b2f    = (const float*)d_in[13];
    float* out = (float*)d_out;                    // reference output is f32

    float* ws    = (float*)d_ws;
    float* qbuf  = ws;                 // 131072 f32
    float* kbuf  = qbuf  + 131072;     // 131072
    float* vbuf  = kbuf  + 131072;     // 131072
    float* qebuf = vbuf  + 131072;     // 524288  qe[b][j][h][c]
    float* pacc  = qebuf + 524288;     // 1048576 [row][jq8][128]
    float* pden  = pacc  + 1048576;    // 1048576
    // total ~11.5 MB workspace (all regions fully written before read)

    tc29_prep<<<256, 256, 0, stream>>>(node, hidden, Wq, Wk, Wv, Wek,
                                       qbuf, kbuf, vbuf, qebuf);
    tc29_attn<<<1024, 256, 0, stream>>>(edge, adj, qbuf, kbuf, vbuf, qebuf,
                                        pacc, pden);
    tc29_post<<<256, 256, 0, stream>>>(pacc, pden, Wo, W1, b1f, W2, b2f, out);
}

// Round 34
// 78.898 us; speedup vs baseline: 1.6738x; 1.6738x over previous
//
#include <hip/hip_runtime.h>

// TransformerConvolution (graph attention with per-edge keys), MI355X gfx950.
// Rewrite: q_j . (edge_ij @ We_k) == edge_ij . (We_k^T q_j) = edge . qe_j
//
// R34: revert to R32 structure (best: 78.5us). R32's VGPR stayed 64 ->
// compiler sank the dual-j prefetch loads to fit 8 waves/SIMD, killing
// memory-level parallelism. __launch_bounds__(256,4) allows 128 VGPR so
// the 16 edge float4 + qe/k operands stay resident -> 2x+ outstanding loads.

__device__ inline float guard_relu(float x) {
    if (x != x) return 0.0f;
    return fmaxf(x, 0.0f);
}

// ---------- Kernel 1: z@{Wq,Wk,Wv}, qe = We_k^T q  (256 blocks x 256) ------
__global__ void tc30_prep(
    const float* node, const float* hidden,
    const float* Wq, const float* Wk, const float* Wv, const float* Wek,
    float* qbuf, float* kbuf, float* vbuf, float* qebuf)
{
    __shared__ float z[4][128];
    __shared__ float qs[4][128];
    const int t = threadIdx.x;
    const int r0 = blockIdx.x * 4;            // global row = b*512 + n

    for (int kk = 0; kk < 2; ++kk) {
        int idx = t + kk * 256;               // 0..511
        int r = idx >> 7, c = idx & 127;
        int row = r0 + r;
        z[r][c] = (c < 64) ? node[row * 64 + c] : hidden[row * 64 + (c - 64)];
    }
    __syncthreads();

    const int o  = t & 127;
    const int rh = t >> 7;                    // rows rh and rh+2
    float aq0 = 0.f, aq1 = 0.f, ak0 = 0.f, ak1 = 0.f, av0 = 0.f, av1 = 0.f;
    for (int c = 0; c < 128; ++c) {
        float wq = Wq[c * 128 + o], wk = Wk[c * 128 + o], wv = Wv[c * 128 + o];
        float z0 = z[rh][c], z1 = z[rh + 2][c];
        aq0 = fmaf(z0, wq, aq0); aq1 = fmaf(z1, wq, aq1);
        ak0 = fmaf(z0, wk, ak0); ak1 = fmaf(z1, wk, ak1);
        av0 = fmaf(z0, wv, av0); av1 = fmaf(z1, wv, av1);
    }
    {
        int row0 = r0 + rh, row1 = r0 + rh + 2;
        qbuf[row0 * 128 + o] = aq0; qbuf[row1 * 128 + o] = aq1;
        kbuf[row0 * 128 + o] = ak0; kbuf[row1 * 128 + o] = ak1;
        vbuf[row0 * 128 + o] = av0; vbuf[row1 * 128 + o] = av1;
        qs[rh][o] = aq0; qs[rh + 2][o] = aq1;
    }
    __syncthreads();

    // qe[row][h][c] = sum_d q[row][h*16+d] * Wek[c*128 + h*16 + d]
    for (int kk = 0; kk < 2; ++kk) {
        int hc = t + kk * 256;                // 0..511
        int h = hc >> 6, c = hc & 63;
        for (int r = 0; r < 4; ++r) {
            float s = 0.f;
            for (int d = 0; d < 16; ++d)
                s = fmaf(qs[r][h * 16 + d], Wek[c * 128 + h * 16 + d], s);
            qebuf[((r0 + r) * 8 + h) * 64 + c] = s;
        }
    }
}

// ---------- Kernel 2: dual-j interleaved score attention (2048 x 256) ------
// block = (b, i-quad(4 rows), j-chunk of 64). 32 groups x 8 lanes; each
// group handles j0=g and j1=g+32. __launch_bounds__(256,4): <=128 VGPR so
// all edge/qe/k operands stay in registers (real prefetch, 2x MLP).
__global__ void __launch_bounds__(256, 4) tc30_attn(
    const float* edge, const float* adj,
    const float* qbuf, const float* kbuf, const float* vbuf,
    const float* qebuf, float* pacc, float* pden)
{
    __shared__ float qls[4][132];
    __shared__ float els[4][8][66];
    const int t   = threadIdx.x;
    const int bid = blockIdx.x;
    const int jq  = bid & 7;                  // 8 chunks of 64 j
    const int it  = (bid >> 3) & 127;         // i-quad
    const int b   = bid >> 10;
    const int i0  = it * 4;

    for (int kk = 0; kk < 2; ++kk) {
        int idx = t + kk * 256;               // 0..511
        int r = idx >> 7, c = idx & 127;
        qls[r][c] = qbuf[(size_t)(b * 512 + i0 + r) * 128 + c];
    }
    __syncthreads();

    const int g = t >> 3;                     // group 0..31
    const int l = t & 7;                      // lane in group

    const int jl0 = g, jl1 = g + 32;
    const int j0 = jq * 64 + jl0;
    const int j1 = jq * 64 + jl1;

    // ---- issue ALL loads for both j's upfront (fits in 128 VGPR now) ----
    const float* e00 = edge + ((size_t)(b * 512 + i0) * 512 + j0) * 64 + l * 8;
    const float* e10 = edge + ((size_t)(b * 512 + i0) * 512 + j1) * 64 + l * 8;
    float4 ea0[4], eb0[4], ea1[4], eb1[4];
    #pragma unroll
    for (int r = 0; r < 4; ++r) {
        const float* p0 = e00 + (size_t)r * 512 * 64;
        const float* p1 = e10 + (size_t)r * 512 * 64;
        ea0[r] = *(const float4*)(p0);
        eb0[r] = *(const float4*)(p0 + 4);
        ea1[r] = *(const float4*)(p1);
        eb1[r] = *(const float4*)(p1 + 4);
    }
    float am0[4], am1[4];
    #pragma unroll
    for (int r = 0; r < 4; ++r) {
        am0[r] = adj[(size_t)(b * 512 + i0 + r) * 512 + j0];
        am1[r] = adj[(size_t)(b * 512 + i0 + r) * 512 + j1];
    }
    const float* qer0 = qebuf + (size_t)(b * 512 + j0) * 512 + l * 8;
    const float* qer1 = qebuf + (size_t)(b * 512 + j1) * 512 + l * 8;
    const float* kr0  = kbuf  + (size_t)(b * 512 + j0) * 128;
    const float* kr1  = kbuf  + (size_t)(b * 512 + j1) * 128;

    #pragma unroll
    for (int h = 0; h < 8; ++h) {
        float4 qa0 = *(const float4*)(qer0 + h * 64);
        float4 qb0 = *(const float4*)(qer0 + h * 64 + 4);
        float4 qa1 = *(const float4*)(qer1 + h * 64);
        float4 qb1 = *(const float4*)(qer1 + h * 64 + 4);
        float k00 = kr0[h * 16 + l], k01 = kr0[h * 16 + 8 + l];
        float k10 = kr1[h * 16 + l], k11 = kr1[h * 16 + 8 + l];
        float p0[4], p1[4];
        #pragma unroll
        for (int r = 0; r < 4; ++r) {
            float qv  = qls[r][h * 16 + l];
            float qvb = qls[r][h * 16 + 8 + l];
            p0[r] = ea0[r].x*qa0.x + ea0[r].y*qa0.y + ea0[r].z*qa0.z + ea0[r].w*qa0.w
                  + eb0[r].x*qb0.x + eb0[r].y*qb0.y + eb0[r].z*qb0.z + eb0[r].w*qb0.w
                  + k00 * qv + k01 * qvb;
            p1[r] = ea1[r].x*qa1.x + ea1[r].y*qa1.y + ea1[r].z*qa1.z + ea1[r].w*qa1.w
                  + eb1[r].x*qb1.x + eb1[r].y*qb1.y + eb1[r].z*qb1.z + eb1[r].w*qb1.w
                  + k10 * qv + k11 * qvb;
        }
        #pragma unroll
        for (int m = 4; m >= 1; m >>= 1) {
            #pragma unroll
            for (int r = 0; r < 4; ++r) {
                p0[r] += __shfl_xor(p0[r], m, 64);   // two independent chains
                p1[r] += __shfl_xor(p1[r], m, 64);
            }
        }
        if (l == h) {
            #pragma unroll
            for (int r = 0; r < 4; ++r) {
                els[r][h][jl0] = am0[r] * __expf(p0[r] * 0.25f);
                els[r][h][jl1] = am1[r] * __expf(p1[r] * 0.25f);
            }
        }
    }
    __syncthreads();

    // ---- PV partials over this 64-j chunk ----
    const int o  = t & 127;                   // outdim (h*16+d)
    const int ip = t >> 7;                    // rows ip, ip+2
    const int hB = o >> 4;
    const float* vbase = vbuf + ((size_t)(b * 512) + jq * 64) * 128 + o;
    float acc0 = 0.f, acc1 = 0.f, d0 = 0.f, d1 = 0.f;
    #pragma unroll 8
    for (int jl = 0; jl < 64; ++jl) {
        float v  = vbase[(size_t)jl * 128];
        float e0 = els[ip][hB][jl];
        float e1 = els[ip + 2][hB][jl];
        acc0 = fmaf(e0, v, acc0); d0 += e0;
        acc1 = fmaf(e1, v, acc1); d1 += e1;
    }
    size_t ix0 = ((size_t)(b * 512 + i0 + ip) * 8 + jq) * 128 + o;
    size_t ix1 = ((size_t)(b * 512 + i0 + ip + 2) * 8 + jq) * 128 + o;
    pacc[ix0] = acc0; pden[ix0] = d0;
    pacc[ix1] = acc1; pden[ix1] = d1;
}

// ---------- Kernel 3: merge 8 chunks + Wo + FFN, f32 store -----------------
__global__ void tc30_post(
    const float* pacc, const float* pden,
    const float* Wo, const float* W1,
    const float* b1f, const float* W2, const float* b2f,
    float* __restrict__ out)
{
    __shared__ float a[4][128];
    __shared__ float y[4][128];
    const int t = threadIdx.x;
    const int o = t & 127, rh = t >> 7;
    const int r0 = blockIdx.x * 4;

    for (int m = 0; m < 2; ++m) {
        int r = rh + 2 * m;
        int row = r0 + r;
        float s = 0.f, d = 0.f;
        #pragma unroll
        for (int q = 0; q < 8; ++q) {
            size_t idx = ((size_t)row * 8 + q) * 128 + o;
            s += pacc[idx];
            d += pden[idx];
        }
        a[r][o] = s / d;                       // adj self-loops -> d > 0
    }
    __syncthreads();

    float acc0 = 0.f, acc1 = 0.f;
    for (int c = 0; c < 128; ++c) {
        float w = Wo[c * 128 + o];
        acc0 = fmaf(a[rh][c], w, acc0);
        acc1 = fmaf(a[rh + 2][c], w, acc1);
    }
    y[rh][o] = acc0; y[rh + 2][o] = acc1;
    __syncthreads();

    acc0 = 0.f; acc1 = 0.f;
    for (int c = 0; c < 128; ++c) {
        float w = W1[c * 128 + o];
        acc0 = fmaf(y[rh][c], w, acc0);
        acc1 = fmaf(y[rh + 2][c], w, acc1);
    }
    float bb = b1f[o];
    __syncthreads();
    a[rh][o]     = guard_relu(acc0 + bb);
    a[rh + 2][o] = guard_relu(acc1 + bb);
    __syncthreads();

    acc0 = 0.f; acc1 = 0.f;
    for (int c = 0; c < 128; ++c) {
        float w = W2[c * 128 + o];
        acc0 = fmaf(a[rh][c], w, acc0);
        acc1 = fmaf(a[rh + 2][c], w, acc1);
    }
    float bb2 = b2f[o];
    int row0 = r0 + rh, row1 = r0 + rh + 2;
    out[row0 * 128 + o] = guard_relu(acc0 + bb2);   // FLOAT32 store
    out[row1 * 128 + o] = guard_relu(acc1 + bb2);
}

extern "C" void kernel_launch(void* const* d_in, const int* in_sizes, int n_in,
                              void* d_out, int out_size, void* d_ws, size_t ws_size,
                              hipStream_t stream) {
    (void)in_sizes; (void)n_in; (void)out_size; (void)ws_size;

    const float* node   = (const float*)d_in[0];
    const float* edge   = (const float*)d_in[1];
    const float* hidden = (const float*)d_in[3];   // d_in[2] = graph_fts, unused
    const float* adj    = (const float*)d_in[4];
    const float* Wq     = (const float*)d_in[5];
    const float* Wk     = (const float*)d_in[6];
    const float* Wv     = (const float*)d_in[7];
    const float* Wo     = (const float*)d_in[8];
    const float* Wek    = (const float*)d_in[9];
    const float* W1     = (const float*)d_in[10];
    const float* b1f    = (const float*)d_in[11];
    const float* W2     = (const float*)d_in[12];
    const float* b2f    = (const float*)d_in[13];
    float* out = (float*)d_out;                    // reference output is f32

    float* ws    = (float*)d_ws;
    float* qbuf  = ws;                 // 131072 f32
    float* kbuf  = qbuf  + 131072;     // 131072
    float* vbuf  = kbuf  + 131072;     // 131072
    float* qebuf = vbuf  + 131072;     // 524288  qe[b][j][h][c]
    float* pacc  = qebuf + 524288;     // 1048576 [row][jq8][128]
    float* pden  = pacc  + 1048576;    // 1048576
    // total ~11.5 MB workspace (all regions fully written before read)

    tc30_prep<<<256, 256, 0, stream>>>(node, hidden, Wq, Wk, Wv, Wek,
                                       qbuf, kbuf, vbuf, qebuf);
    tc30_attn<<<2048, 256, 0, stream>>>(edge, adj, qbuf, kbuf, vbuf, qebuf,
                                        pacc, pden);
    tc30_post<<<256, 256, 0, stream>>>(pacc, pden, Wo, W1, b1f, W2, b2f, out);
}